// Round 1
// baseline (259.498 us; speedup 1.0000x reference)
//
#include <hip/hip_runtime.h>

// ScaledDotProductAttention fwd: out0 = attn output [2,16,2048,64] f32,
// out1 = attn weights [2,16,2048,2048] f32.
// Two-pass per 64-row q-tile: pass1 = QK^T -> exp -> rowsum l, O += e*V (MFMA);
// pass2 = recompute QK^T, store e/l (nontemporal). No max-subtraction (scores
// are O(6); exp fp32-safe; identical math to softmax). Mask pre-packed to bits.

typedef __attribute__((ext_vector_type(4))) float f32x4;
typedef __attribute__((ext_vector_type(4))) int   i32x4;

#define S_LEN 2048
#define D_DIM 64
#define H_NUM 16
#define B_NUM 2
#define NT    32   // S/64 k-tiles
#define SW    32   // mask words per row (S/64)

// XOR swizzle within a 128-byte (64 bf16) row: makes the "16 rows read the
// same 16B column slot" MFMA fragment pattern bank-conflict-free.
__device__ __forceinline__ int swz(int row, int colByte) {
  return row * 128 + (colByte ^ ((row & 7) << 4));
}

__device__ __forceinline__ unsigned short f2bf(float f) {  // RNE f32->bf16
  unsigned int x = __builtin_bit_cast(unsigned int, f);
  x = (x + 0x7FFFu + ((x >> 16) & 1u)) >> 16;
  return (unsigned short)x;
}

__device__ __forceinline__ void mfma16(f32x4& acc, i32x4 a, i32x4 b) {
  asm("v_mfma_f32_16x16x32_bf16 %0, %1, %2, %0" : "+v"(acc) : "v"(a), "v"(b));
}

__global__ __launch_bounds__(256) void mask_pack_kernel(const int* __restrict__ m,
                                                        unsigned long long* __restrict__ bits) {
  const int total = B_NUM * S_LEN * S_LEN;     // 8388608
  const int step  = gridDim.x * blockDim.x;    // 262144 -> 32 uniform iters
  for (int i = blockIdx.x * blockDim.x + threadIdx.x; i < total; i += step) {
    unsigned long long b = __ballot(m[i] != 0);
    if ((threadIdx.x & 63) == 0) bits[i >> 6] = b;
  }
}

template <int USE_BITS>
__global__ __launch_bounds__(256) void attn_fwd_kernel(
    const float* __restrict__ Qp, const float* __restrict__ Kp, const float* __restrict__ Vp,
    const unsigned long long* __restrict__ Mb, const int* __restrict__ Mi,
    float* __restrict__ Op, float* __restrict__ Wp)
{
  const int tid  = threadIdx.x;
  const int lane = tid & 63;
  const int wv   = tid >> 6;     // wave 0..3, owns q-rows wv*16..+15
  const int l15  = lane & 15;
  const int g4   = lane >> 4;

  // Bijective XCD swizzle (1024 % 8 == 0): each XCD gets a contiguous logical
  // chunk. Logical order qt-fastest so co-resident blocks share (b,h) K/V in L2.
  const int wg = blockIdx.x;
  const int lg = (wg & 7) * 128 + (wg >> 3);
  const int qt = lg & 31;
  const int bh = lg >> 5;        // b*H + h
  const int b  = bh >> 4;

  __shared__ __align__(16) char lds[32768];
  char* Qs  = lds;                          // [64][64] bf16 swizzled
  char* Ks  = lds + 8192;                   // [64][64] bf16 swizzled
  char* VTs = lds + 16384;                  // [64 v][64 k] bf16 swizzled (V^T)
  char* Ps  = lds + 24576 + (wv << 11);     // per-wave [16][64] bf16 swizzled

  const float* Qg = Qp + ((size_t)bh * S_LEN + qt * 64) * D_DIM;
  const float* Kg = Kp + (size_t)bh * S_LEN * D_DIM;
  const float* Vg = Vp + (size_t)bh * S_LEN * D_DIM;
  float* Og = Op + ((size_t)bh * S_LEN + qt * 64) * D_DIM;
  float* Wg = Wp + ((size_t)bh * S_LEN + qt * 64) * S_LEN;
  const unsigned long long* Mg = Mb + ((size_t)b * S_LEN + qt * 64) * SW;
  const int* Mig = Mi + ((size_t)b * S_LEN + qt * 64) * S_LEN;

  // ---- stage Q once ----
  {
    const int r0 = tid >> 4;
    const int c  = (tid & 15) * 4;
#pragma unroll
    for (int i = 0; i < 4; ++i) {
      const int r = r0 + i * 16;
      float4 v = *(const float4*)(Qg + r * D_DIM + c);
      ushort4 p; p.x = f2bf(v.x); p.y = f2bf(v.y); p.z = f2bf(v.z); p.w = f2bf(v.w);
      *(ushort4*)(Qs + swz(r, c * 2)) = p;
    }
  }
  __syncthreads();
  const i32x4 qa0 = *(const i32x4*)(Qs + swz(wv * 16 + l15, g4 * 16));
  const i32x4 qa1 = *(const i32x4*)(Qs + swz(wv * 16 + l15, g4 * 16 + 64));

  f32x4 oacc[4];
#pragma unroll
  for (int i = 0; i < 4; ++i) oacc[i] = f32x4{0.f, 0.f, 0.f, 0.f};
  float lp[4] = {0.f, 0.f, 0.f, 0.f};

  const int qrow = wv * 16 + g4 * 4;   // first of this lane's 4 acc rows (in-tile)

  // ================= PASS 1: rowsum + O accumulate =================
  for (int kt = 0; kt < NT; ++kt) {
    __syncthreads();
    {
      const int r0 = tid >> 4;
      const int c  = (tid & 15) * 4;
      const float* Kt = Kg + kt * 64 * D_DIM;
#pragma unroll
      for (int i = 0; i < 4; ++i) {
        const int r = r0 + i * 16;
        float4 v = *(const float4*)(Kt + r * D_DIM + c);
        ushort4 p; p.x = f2bf(v.x); p.y = f2bf(v.y); p.z = f2bf(v.z); p.w = f2bf(v.w);
        *(ushort4*)(Ks + swz(r, c * 2)) = p;
      }
      // V staged transposed: VTs[v][k]; pack rows (rr, rr+1) into one b32 write
      const float* Vt = Vg + kt * 64 * D_DIM;
#pragma unroll
      for (int i = 0; i < 2; ++i) {
        const int rr = (tid >> 4) * 2 + i * 32;
        float4 a  = *(const float4*)(Vt + rr * D_DIM + c);
        float4 bq = *(const float4*)(Vt + (rr + 1) * D_DIM + c);
        const float av[4] = {a.x, a.y, a.z, a.w};
        const float bv[4] = {bq.x, bq.y, bq.z, bq.w};
#pragma unroll
        for (int j = 0; j < 4; ++j) {
          unsigned pk = (unsigned)f2bf(av[j]) | ((unsigned)f2bf(bv[j]) << 16);
          *(unsigned*)(VTs + swz(c + j, rr * 2)) = pk;
        }
      }
    }
    __syncthreads();

    unsigned long long mw[4] = {0, 0, 0, 0};
    if (USE_BITS) {
#pragma unroll
      for (int r = 0; r < 4; ++r) mw[r] = Mg[(qrow + r) * SW + kt];
    }

    f32x4 sacc[4];
#pragma unroll
    for (int i = 0; i < 4; ++i) sacc[i] = f32x4{0.f, 0.f, 0.f, 0.f};
#pragma unroll
    for (int ct = 0; ct < 4; ++ct) {
      i32x4 b0 = *(const i32x4*)(Ks + swz(ct * 16 + l15, g4 * 16));
      i32x4 b1 = *(const i32x4*)(Ks + swz(ct * 16 + l15, g4 * 16 + 64));
      mfma16(sacc[ct], qa0, b0);
      mfma16(sacc[ct], qa1, b1);
    }

#pragma unroll
    for (int ct = 0; ct < 4; ++ct) {
#pragma unroll
      for (int r = 0; r < 4; ++r) {
        float e = __expf(sacc[ct][r] * 0.125f);
        bool keep;
        if (USE_BITS) keep = (mw[r] >> (ct * 16 + l15)) & 1ull;
        else          keep = Mig[(size_t)(qrow + r) * S_LEN + kt * 64 + ct * 16 + l15] != 0;
        e = keep ? e : 0.f;
        lp[r] += e;
        *(unsigned short*)(Ps + swz(g4 * 4 + r, (ct * 16 + l15) * 2)) = f2bf(e);
      }
    }
    // wave-internal cross-lane LDS hazard: drain DS queue, pin the reads after
    asm volatile("s_waitcnt lgkmcnt(0)" ::: "memory");
    __builtin_amdgcn_sched_barrier(0);

    const i32x4 pa0 = *(const i32x4*)(Ps + swz(l15, g4 * 16));
    const i32x4 pa1 = *(const i32x4*)(Ps + swz(l15, g4 * 16 + 64));
#pragma unroll
    for (int ct = 0; ct < 4; ++ct) {
      i32x4 v0 = *(const i32x4*)(VTs + swz(ct * 16 + l15, g4 * 16));
      i32x4 v1 = *(const i32x4*)(VTs + swz(ct * 16 + l15, g4 * 16 + 64));
      mfma16(oacc[ct], pa0, v0);
      mfma16(oacc[ct], pa1, v1);
    }
  }

  // rowsum reduce across the 16-lane column group; keep reciprocal
#pragma unroll
  for (int r = 0; r < 4; ++r) {
    float v = lp[r];
    v += __shfl_xor(v, 1);
    v += __shfl_xor(v, 2);
    v += __shfl_xor(v, 4);
    v += __shfl_xor(v, 8);
    lp[r] = 1.0f / v;
  }

#pragma unroll
  for (int ct = 0; ct < 4; ++ct)
#pragma unroll
    for (int r = 0; r < 4; ++r)
      Og[(size_t)(qrow + r) * D_DIM + ct * 16 + l15] = oacc[ct][r] * lp[r];

  // ================= PASS 2: recompute scores, stream weights =================
  for (int kt = 0; kt < NT; ++kt) {
    __syncthreads();
    {
      const int r0 = tid >> 4;
      const int c  = (tid & 15) * 4;
      const float* Kt = Kg + kt * 64 * D_DIM;
#pragma unroll
      for (int i = 0; i < 4; ++i) {
        const int r = r0 + i * 16;
        float4 v = *(const float4*)(Kt + r * D_DIM + c);
        ushort4 p; p.x = f2bf(v.x); p.y = f2bf(v.y); p.z = f2bf(v.z); p.w = f2bf(v.w);
        *(ushort4*)(Ks + swz(r, c * 2)) = p;
      }
    }
    __syncthreads();

    unsigned long long mw[4] = {0, 0, 0, 0};
    if (USE_BITS) {
#pragma unroll
      for (int r = 0; r < 4; ++r) mw[r] = Mg[(qrow + r) * SW + kt];
    }

    f32x4 sacc[4];
#pragma unroll
    for (int i = 0; i < 4; ++i) sacc[i] = f32x4{0.f, 0.f, 0.f, 0.f};
#pragma unroll
    for (int ct = 0; ct < 4; ++ct) {
      i32x4 b0 = *(const i32x4*)(Ks + swz(ct * 16 + l15, g4 * 16));
      i32x4 b1 = *(const i32x4*)(Ks + swz(ct * 16 + l15, g4 * 16 + 64));
      mfma16(sacc[ct], qa0, b0);
      mfma16(sacc[ct], qa1, b1);
    }

#pragma unroll
    for (int ct = 0; ct < 4; ++ct) {
#pragma unroll
      for (int r = 0; r < 4; ++r) {
        float e = __expf(sacc[ct][r] * 0.125f);
        bool keep;
        if (USE_BITS) keep = (mw[r] >> (ct * 16 + l15)) & 1ull;
        else          keep = Mig[(size_t)(qrow + r) * S_LEN + kt * 64 + ct * 16 + l15] != 0;
        e = keep ? e : 0.f;
        __builtin_nontemporal_store(e * lp[r],
            Wg + (size_t)(qrow + r) * S_LEN + kt * 64 + ct * 16 + l15);
      }
    }
  }
}

extern "C" void kernel_launch(void* const* d_in, const int* in_sizes, int n_in,
                              void* d_out, int out_size, void* d_ws, size_t ws_size,
                              hipStream_t stream) {
  (void)in_sizes; (void)n_in; (void)out_size;
  const float* Q   = (const float*)d_in[0];
  const float* K   = (const float*)d_in[1];
  const float* V   = (const float*)d_in[2];
  const int* mask  = (const int*)d_in[3];
  float* Out = (float*)d_out;
  float* W   = Out + (size_t)B_NUM * H_NUM * S_LEN * D_DIM;   // 4194304

  const size_t bits_bytes = (size_t)(B_NUM * S_LEN * S_LEN / 64) * 8;  // 1 MiB
  unsigned long long* bits = (unsigned long long*)d_ws;

  if (ws_size >= bits_bytes) {
    mask_pack_kernel<<<1024, 256, 0, stream>>>(mask, bits);
    attn_fwd_kernel<1><<<1024, 256, 0, stream>>>(Q, K, V, bits, mask, Out, W);
  } else {
    attn_fwd_kernel<0><<<1024, 256, 0, stream>>>(Q, K, V, bits, mask, Out, W);
  }
}